// Round 1
// 310.561 us; speedup vs baseline: 1.0004x; 1.0004x over previous
//
#include <hip/hip_runtime.h>
#include <math.h>

#define BB   1024
#define DD   768
#define HIDV 384
#define MLPH 300
#define MLPP 320   // padded to multiple of 64

typedef float v2f __attribute__((ext_vector_type(2)));

__device__ __forceinline__ float softplusf(float x) {
    return (x > 20.f) ? x : log1pf(expf(x));
}

// ---------------- init: zero accumulators (accum[16] + sumexp[1024]) ----------------
__global__ void k_init(float* __restrict__ ws) {
    int i = blockIdx.x * 256 + threadIdx.x;
    if (i < 16 + BB) ws[i] = 0.f;
}

// ---------------- A: direct-to-register z-reduce + sample + KL ----------------
// One block (192 thr, 3 waves) per row b. Thread t owns float4 d-chunk
// [4t, 4t+4) of the 768-wide z1/z2 rows. The s-reduction (20 zl rows + 36 zv
// rows) accumulates straight into VGPRs: data is single-use, so no LDS
// staging (old version: 60.5 KB LDS -> 2 blocks/CU, 6 vmcnt stalls/wave;
// this version: ~3 KB LDS -> 4 blocks/CU resident, 56 independent float4
// loads/thread for MLP).
__global__ __launch_bounds__(192, 3) void k_rs(
    const float* __restrict__ zl, const float* __restrict__ zv,
    const float* __restrict__ wl, const float* __restrict__ blp,
    const float* __restrict__ wv, const float* __restrict__ bvp,
    const float* __restrict__ eps1, const float* __restrict__ eps2,
    float* __restrict__ s1, float* __restrict__ s2, float* __restrict__ accum)
{
    __shared__ float SG[768];    // softplus'd sigma halves: sig1 [0,384), sig2 [384,768)
    __shared__ float pr[3];
    int tid = threadIdx.x;       // 0..191
    int b = blockIdx.x;

    const float4* zl4 = (const float4*)(zl + (size_t)b * 15360) + tid;  // 20*768
    const float4* zv4 = (const float4*)(zv + (size_t)b * 27648) + tid;  // 36*768

    float a1[4] = {0.f, 0.f, 0.f, 0.f};
    float a2[4] = {0.f, 0.f, 0.f, 0.f};

    #pragma unroll
    for (int s = 0; s < 20; ++s) {
        float4 v = zl4[s * 192];           // row stride 768 floats = 192 float4
        float w = wl[s];                   // uniform -> SGPR
        a1[0] = fmaf(v.x, w, a1[0]);
        a1[1] = fmaf(v.y, w, a1[1]);
        a1[2] = fmaf(v.z, w, a1[2]);
        a1[3] = fmaf(v.w, w, a1[3]);
    }
    #pragma unroll
    for (int s = 0; s < 36; ++s) {
        float4 v = zv4[s * 192];
        float w = wv[s];
        a2[0] = fmaf(v.x, w, a2[0]);
        a2[1] = fmaf(v.y, w, a2[1]);
        a2[2] = fmaf(v.z, w, a2[2]);
        a2[3] = fmaf(v.w, w, a2[3]);
    }

    float bl = blp[0], bv = bvp[0];

    // threads 96..191 own d in [384,768): the sigma halves. softplus + stash.
    if (tid >= 96) {
        float o1[4], o2[4];
        #pragma unroll
        for (int j = 0; j < 4; ++j) {
            o1[j] = softplusf(a1[j] + bl) + 1e-7f;
            o2[j] = softplusf(a2[j] + bv) + 1e-7f;
        }
        *(float4*)(SG + (tid - 96) * 4)       = make_float4(o1[0], o1[1], o1[2], o1[3]);
        *(float4*)(SG + 384 + (tid - 96) * 4) = make_float4(o2[0], o2[1], o2[2], o2[3]);
    }
    __syncthreads();

    float con = 0.f;
    if (tid < 96) {
        float4 e1v = ((const float4*)eps1)[b * 96 + tid];
        float4 e2v = ((const float4*)eps2)[b * 96 + tid];
        float e1a[4] = {e1v.x, e1v.y, e1v.z, e1v.w};
        float e2a[4] = {e2v.x, e2v.y, e2v.z, e2v.w};
        float4 g1 = *(const float4*)(SG + tid * 4);
        float4 g2 = *(const float4*)(SG + 384 + tid * 4);
        float g1a[4] = {g1.x, g1.y, g1.z, g1.w};
        float g2a[4] = {g2.x, g2.y, g2.z, g2.w};
        float s1o[4], s2o[4];
        #pragma unroll
        for (int j = 0; j < 4; ++j) {
            float mu1 = a1[j] + bl;
            float mu2 = a2[j] + bv;
            float sg1 = g1a[j], sg2 = g2a[j];
            float e1 = e1a[j], e2 = e2a[j];
            float sv1 = fmaf(sg1, e1, mu1);
            float sv2 = fmaf(sg2, e2, mu2);
            s1o[j] = sv1; s2o[j] = sv2;
            float z12 = (sv1 - mu2) / sg2;
            float z21 = (sv2 - mu1) / sg1;
            con += -0.5f * (e1 * e1 + e2 * e2) + 0.5f * z12 * z12 + 0.5f * z21 * z21;
        }
        ((float4*)s1)[b * 96 + tid] = make_float4(s1o[0], s1o[1], s1o[2], s1o[3]);
        ((float4*)s2)[b * 96 + tid] = make_float4(s2o[0], s2o[1], s2o[2], s2o[3]);
    }

    #pragma unroll
    for (int m = 1; m < 64; m <<= 1) con += __shfl_xor(con, m);
    if ((tid & 63) == 0) pr[tid >> 6] = con;
    __syncthreads();
    if (tid == 0) atomicAdd(&accum[0], pr[0] + pr[1] + pr[2]);
}

// ---------------- B: Axb = s1 @ W1x^T + b1 (padded), By = s2 @ W1y^T ----------------
__global__ __launch_bounds__(256) void k_gemm(
    const float* __restrict__ s1, const float* __restrict__ s2,
    const float* __restrict__ W1, const float* __restrict__ b1,
    float* __restrict__ Axb, float* __restrict__ By)
{
    __shared__ __align__(16) float Ss[32][36];   // [h][b] 32x32
    __shared__ __align__(16) float Ws[32][68];   // [h][k] 32x64
    int z = blockIdx.z;
    const float* S = z ? s2 : s1;
    float* Out = z ? By : Axb;
    int wofs = z ? HIDV : 0;
    int b0 = blockIdx.x * 32;
    int k0 = blockIdx.y * 64;
    int tid = threadIdx.x;
    int srow = tid >> 3, sc = tid & 7;
    int wrow = tid >> 2, wc = tid & 3;
    int krow = k0 + wrow;
    int tx = tid & 15, ty = tid >> 4;

    float4 ps, pw[2];
    auto ld = [&](int hc) {
        ps = *(const float4*)&S[(b0 + srow) * HIDV + hc + sc * 4];
        #pragma unroll
        for (int u = 0; u < 2; ++u)
            pw[u] = (krow < MLPH) ? *(const float4*)&W1[krow * DD + wofs + hc + wc * 4 + u * 16]
                                  : make_float4(0.f, 0.f, 0.f, 0.f);
    };
    ld(0);
    v2f acc[2][2];
    acc[0][0] = (v2f){0.f, 0.f}; acc[0][1] = (v2f){0.f, 0.f};
    acc[1][0] = (v2f){0.f, 0.f}; acc[1][1] = (v2f){0.f, 0.f};

    for (int ch = 0; ch < 12; ++ch) {
        __syncthreads();
        Ss[sc * 4 + 0][srow] = ps.x; Ss[sc * 4 + 1][srow] = ps.y;
        Ss[sc * 4 + 2][srow] = ps.z; Ss[sc * 4 + 3][srow] = ps.w;
        #pragma unroll
        for (int u = 0; u < 2; ++u) {
            int hb = wc * 4 + u * 16;
            Ws[hb + 0][wrow] = pw[u].x; Ws[hb + 1][wrow] = pw[u].y;
            Ws[hb + 2][wrow] = pw[u].z; Ws[hb + 3][wrow] = pw[u].w;
        }
        __syncthreads();
        if (ch < 11) ld((ch + 1) * 32);
        #pragma unroll
        for (int h = 0; h < 32; ++h) {
            v2f sv = *(const v2f*)&Ss[h][ty * 2];
            float4 wq = *(const float4*)&Ws[h][tx * 4];
            v2f w0 = (v2f){wq.x, wq.y};
            v2f w1 = (v2f){wq.z, wq.w};
            v2f s0 = (v2f){sv.x, sv.x};
            v2f s1b = (v2f){sv.y, sv.y};
            acc[0][0] = __builtin_elementwise_fma(s0, w0, acc[0][0]);
            acc[0][1] = __builtin_elementwise_fma(s0, w1, acc[0][1]);
            acc[1][0] = __builtin_elementwise_fma(s1b, w0, acc[1][0]);
            acc[1][1] = __builtin_elementwise_fma(s1b, w1, acc[1][1]);
        }
    }
    #pragma unroll
    for (int i = 0; i < 2; ++i) {
        int bb = b0 + ty * 2 + i;
        float vraw[4] = {acc[i][0].x, acc[i][0].y, acc[i][1].x, acc[i][1].y};
        float o[4];
        #pragma unroll
        for (int j = 0; j < 4; ++j) {
            int k = k0 + tx * 4 + j;
            float v = vraw[j];
            if (!z) v += b1[k < MLPH ? k : 0];
            o[j] = (k < MLPH) ? v : 0.f;
        }
        *(float4*)&Out[bb * MLPP + k0 + tx * 4] = make_float4(o[0], o[1], o[2], o[3]);
    }
}

// ---------------- C: T0 sum ----------------
__global__ void k_t0(const float* __restrict__ Axb, const float* __restrict__ By,
                     const float* __restrict__ W2, const float* __restrict__ b2,
                     float* __restrict__ accum)
{
    int b = blockIdx.x;
    int l = threadIdx.x;  // 64
    float t = 0.f;
    for (int k = l; k < MLPH; k += 64)
        t = fmaf(fmaxf(Axb[b * MLPP + k] + By[b * MLPP + k], 0.f), W2[k], t);
    #pragma unroll
    for (int m = 1; m < 64; m <<= 1) t += __shfl_xor(t, m);
    if (l == 0) atomicAdd(&accum[1], softplusf(t + b2[0]));
}

// ---------------- D: pair kernel, packed math, fused sumexp(T1) ----------------
__global__ __launch_bounds__(256) void k_pairs(
    const float* __restrict__ Axb, const float* __restrict__ By,
    const int* __restrict__ perm, const float* __restrict__ W2,
    const float* __restrict__ b2, float* __restrict__ sumexp)
{
    __shared__ __align__(16) float As[64][68];   // [k][j]
    __shared__ __align__(16) float Bs[64][68];   // [k][i]
    __shared__ float w2s[MLPP];
    int tid = threadIdx.x;
    int j0 = blockIdx.x * 64;
    int i0 = blockIdx.y * 64;
    for (int t = tid; t < MLPP; t += 256) w2s[t] = (t < MLPH) ? W2[t] : 0.f;
    int r = tid >> 2;          // 0..63
    int c4 = tid & 3;
    int tx = tid & 15, ty = tid >> 4;
    int prow = perm[i0 + r];

    float4 pa[4], pb[4];
    auto ld = [&](int kc) {
        #pragma unroll
        for (int u = 0; u < 4; ++u) {
            int kq = (c4 + 4 * u) * 4;   // 0..60
            pa[u] = *(const float4*)&Axb[(j0 + r) * MLPP + kc + kq];
            pb[u] = *(const float4*)&By[prow * MLPP + kc + kq];
        }
    };
    ld(0);
    v2f acc2[4][2];
    #pragma unroll
    for (int c = 0; c < 4; ++c) {
        acc2[c][0] = (v2f){0.f, 0.f};
        acc2[c][1] = (v2f){0.f, 0.f};
    }
    for (int ch = 0; ch < 5; ++ch) {
        __syncthreads();
        #pragma unroll
        for (int u = 0; u < 4; ++u) {
            int kq = (c4 + 4 * u) * 4;
            As[kq + 0][r] = pa[u].x; As[kq + 1][r] = pa[u].y;
            As[kq + 2][r] = pa[u].z; As[kq + 3][r] = pa[u].w;
            Bs[kq + 0][r] = pb[u].x; Bs[kq + 1][r] = pb[u].y;
            Bs[kq + 2][r] = pb[u].z; Bs[kq + 3][r] = pb[u].w;
        }
        __syncthreads();
        if (ch < 4) ld((ch + 1) * 64);
        int kc = ch * 64;
        #pragma unroll
        for (int k = 0; k < 64; ++k) {
            float w = w2s[kc + k];
            v2f wv2 = (v2f){w, w};
            float4 af = *(const float4*)&As[k][tx * 4];
            float4 bf = *(const float4*)&Bs[k][ty * 4];
            v2f a2[2] = { (v2f){af.x, af.y}, (v2f){af.z, af.w} };
            float bs[4] = {bf.x, bf.y, bf.z, bf.w};
            #pragma unroll
            for (int c = 0; c < 4; ++c) {
                v2f bc = (v2f){bs[c], bs[c]};
                #pragma unroll
                for (int d2 = 0; d2 < 2; ++d2) {
                    v2f tv = a2[d2] + bc;
                    tv = __builtin_elementwise_max(tv, (v2f){0.f, 0.f});
                    acc2[c][d2] = __builtin_elementwise_fma(tv, wv2, acc2[c][d2]);
                }
            }
        }
    }
    float b2v = b2[0];
    #pragma unroll
    for (int c = 0; c < 4; ++c) {
        float vv[4] = {acc2[c][0].x, acc2[c][0].y, acc2[c][1].x, acc2[c][1].y};
        float ssum = 0.f;
        #pragma unroll
        for (int d = 0; d < 4; ++d)
            ssum += 1.f + expf(vv[d] + b2v);   // exp(softplus(x)) == 1 + exp(x)
        ssum += __shfl_xor(ssum, 1);
        ssum += __shfl_xor(ssum, 2);
        ssum += __shfl_xor(ssum, 4);
        ssum += __shfl_xor(ssum, 8);
        if (tx == 0) atomicAdd(&sumexp[i0 + ty * 4 + c], ssum);
    }
}

// ---------------- E: final scalar ----------------
__global__ __launch_bounds__(256) void k_final(
    const float* __restrict__ accum, const float* __restrict__ sumexp,
    float* __restrict__ out)
{
    int tid = threadIdx.x;
    float s = 0.f;
    for (int i = tid; i < BB; i += 256) s += logf(sumexp[i]);
    #pragma unroll
    for (int m = 1; m < 64; m <<= 1) s += __shfl_xor(s, m);
    __shared__ float red[4];
    if ((tid & 63) == 0) red[tid >> 6] = s;
    __syncthreads();
    if (tid == 0) {
        float lse_mean = (red[0] + red[1] + red[2] + red[3]) / (float)BB;
        float d_skl = accum[0] / (2.f * (float)BB);
        float t0_mean = accum[1] / (float)BB;
        float lower = t0_mean - (lse_mean - logf((float)BB));
        out[0] = d_skl - lower;
    }
}

extern "C" void kernel_launch(void* const* d_in, const int* in_sizes, int n_in,
                              void* d_out, int out_size, void* d_ws, size_t ws_size,
                              hipStream_t stream)
{
    const float* zl     = (const float*)d_in[0];
    const float* zv     = (const float*)d_in[1];
    const float* fc_l_w = (const float*)d_in[2];
    const float* fc_l_b = (const float*)d_in[3];
    const float* fc_v_w = (const float*)d_in[4];
    const float* fc_v_b = (const float*)d_in[5];
    const float* W1     = (const float*)d_in[6];
    const float* b1     = (const float*)d_in[7];
    const float* W2     = (const float*)d_in[8];
    const float* b2     = (const float*)d_in[9];
    const float* eps1   = (const float*)d_in[10];
    const float* eps2   = (const float*)d_in[11];
    const int*   perm   = (const int*)d_in[12];
    float* out = (float*)d_out;

    float* ws     = (float*)d_ws;
    float* accum  = ws;                    // 16
    float* sumexp = ws + 16;               // 1024
    float* s1     = ws + 16 + BB;          // B*384
    float* s2     = s1 + BB * HIDV;        // B*384
    float* Axb    = s2 + BB * HIDV;        // B*320
    float* By     = Axb + BB * MLPP;       // B*320

    k_init<<<5, 256, 0, stream>>>(ws);
    k_rs<<<BB, 192, 0, stream>>>(zl, zv, fc_l_w, fc_l_b, fc_v_w, fc_v_b,
                                 eps1, eps2, s1, s2, accum);
    k_gemm<<<dim3(32, 5, 2), 256, 0, stream>>>(s1, s2, W1, b1, Axb, By);
    k_t0<<<BB, 64, 0, stream>>>(Axb, By, W2, b2, accum);
    k_pairs<<<dim3(16, 16), 256, 0, stream>>>(Axb, By, perm, W2, b2, sumexp);
    k_final<<<1, 256, 0, stream>>>(accum, sumexp, out);
}